// Round 1
// baseline (104.109 us; speedup 1.0000x reference)
//
#include <hip/hip_runtime.h>
#include <math.h>

// Spectral solution of the ring RNN:
//   r_record[s] = M^s (h / tau),  M = (1-c) I + c W,  c = dt/tau = 0.05
// W is circulant (W[i,j] = V(phi_i - phi_j)), so M diagonalizes in the ring
// Fourier basis; h (von-Mises bump) is band-limited to |k| <= ~16 at fp32.
// Keep K=20 harmonics:
//   r_s[i,b] = (1/(n*tau)) [ lam_0^s u_0(b)
//              + 2 sum_k lam_k^s (u_k(b) cos k phi_i + v_k(b) sin k phi_i) ]
// with w_k = DFT of W row 0, lam_k = 0.95 + 0.05 w_k,
//      u_k(b) = sum_i h[i,b] cos k phi_i, v_k(b) = sum_i h[i,b] sin k phi_i.

#define NN      4096
#define NB      256
#define NSTEPS  61
#define KM      20
#define NJ      41            // 1 + KM cos + KM sin basis functions

#define PHI_STEP 0.0015339807878856412f   // 2*pi/4096
#define INV_K2   1.6211389382774044f      // 1/kappa^2 = 16/pi^2

// ws layout (floats)
#define L_OFF   64            // lambda powers: [61][KM+1]
#define UV_OFF  2048          // coefficients: [NJ][NB]

__device__ __forceinline__ float phiF(int i) { return PHI_STEP * (float)i; }

// --- kernel A: w_k from W row 0 -> lambda^s table; also writes t_record ---
__global__ void rnn_ring_kA(const float* __restrict__ W,
                            float* __restrict__ ws,
                            float* __restrict__ out) {
    int tid = threadIdx.x;
    float acc[KM + 1];
#pragma unroll
    for (int k = 0; k <= KM; ++k) acc[k] = 0.0f;

    for (int j = tid; j < NN; j += 256) {
        float w  = W[j];                   // row 0 of W
        float ph = phiF(j);
        float c1 = cosf(ph);
        acc[0] += w;
        acc[1] += w * c1;
        float ckm1 = 1.0f, ck = c1;
#pragma unroll
        for (int k = 2; k <= KM; ++k) {
            float cn = 2.0f * c1 * ck - ckm1;
            ckm1 = ck; ck = cn;
            acc[k] += w * cn;
        }
    }
#pragma unroll
    for (int k = 0; k <= KM; ++k) {
        float x = acc[k];
        x += __shfl_xor(x, 32); x += __shfl_xor(x, 16); x += __shfl_xor(x, 8);
        x += __shfl_xor(x, 4);  x += __shfl_xor(x, 2);  x += __shfl_xor(x, 1);
        acc[k] = x;
    }
    __shared__ float red[4][KM + 1];
    int wid = tid >> 6, lane = tid & 63;
    if (lane == 0) {
#pragma unroll
        for (int k = 0; k <= KM; ++k) red[wid][k] = acc[k];
    }
    __syncthreads();
    if (tid <= KM) {
        float wk  = red[0][tid] + red[1][tid] + red[2][tid] + red[3][tid];
        float lam = 0.95f + 0.05f * wk;    // (1-c) + c*w_k
        float p = 1.0f;
        for (int s = 0; s < NSTEPS; ++s) {
            ws[L_OFF + s * (KM + 1) + tid] = p;
            p *= lam;
        }
    }
    if (tid >= 64 && tid < 64 + NSTEPS) {
        out[tid - 64] = 0.001f * (float)(tid - 64);   // t_record = dt * s
    }
}

// --- kernel B: mode projections of h(theta_b): uv[j][b] ---
__global__ void rnn_ring_kB(const float* __restrict__ theta,
                            float* __restrict__ ws) {
    int b   = blockIdx.x;
    int tid = threadIdx.x;
    float th = theta[b];

    float uv[NJ];
#pragma unroll
    for (int j = 0; j < NJ; ++j) uv[j] = 0.0f;

    for (int i = tid; i < NN; i += 256) {
        float ph = phiF(i);
        float hh = expf((cosf(ph - th) - 1.0f) * INV_K2);
        float c1 = cosf(ph), s1 = sinf(ph);
        uv[0]      += hh;
        uv[1]      += hh * c1;
        uv[KM + 1] += hh * s1;
        float ckm1 = 1.0f, skm1 = 0.0f, ck = c1, sk = s1;
#pragma unroll
        for (int k = 2; k <= KM; ++k) {
            float cn = 2.0f * c1 * ck - ckm1;
            float sn = 2.0f * c1 * sk - skm1;
            ckm1 = ck; skm1 = sk; ck = cn; sk = sn;
            uv[k]      += hh * cn;
            uv[KM + k] += hh * sn;
        }
    }
#pragma unroll
    for (int j = 0; j < NJ; ++j) {
        float x = uv[j];
        x += __shfl_xor(x, 32); x += __shfl_xor(x, 16); x += __shfl_xor(x, 8);
        x += __shfl_xor(x, 4);  x += __shfl_xor(x, 2);  x += __shfl_xor(x, 1);
        uv[j] = x;
    }
    __shared__ float red[4][NJ];
    int wid = tid >> 6, lane = tid & 63;
    if (lane == 0) {
#pragma unroll
        for (int j = 0; j < NJ; ++j) red[wid][j] = uv[j];
    }
    __syncthreads();
    if (tid < NJ) {
        float x = red[0][tid] + red[1][tid] + red[2][tid] + red[3][tid];
        ws[UV_OFF + tid * NB + b] = x;
    }
}

// --- kernel C: synthesis. block = (s, 64-row i-tile); 8x8 fp32 micro-tiles ---
__global__ void __launch_bounds__(256)
rnn_ring_kC(const float* __restrict__ ws, float* __restrict__ out) {
    int blk = blockIdx.x;
    int s   = blk >> 6;
    int i0  = (blk & 63) << 6;
    int tid = threadIdx.x;

    __shared__ float Tsh[NJ * 64];    // basis [j][i_local]
    __shared__ float Psh[NJ * NB];    // lam^s-scaled coefficients [j][b]

    if (tid < 64) {                   // basis via Chebyshev recurrence
        int   i  = i0 + tid;
        float ph = phiF(i);
        float c1 = cosf(ph), s1 = sinf(ph);
        Tsh[0 * 64 + tid]        = 1.0f;
        Tsh[1 * 64 + tid]        = c1;
        Tsh[(KM + 1) * 64 + tid] = s1;
        float ckm1 = 1.0f, skm1 = 0.0f, ck = c1, sk = s1;
#pragma unroll
        for (int k = 2; k <= KM; ++k) {
            float cn = 2.0f * c1 * ck - ckm1;
            float sn = 2.0f * c1 * sk - skm1;
            ckm1 = ck; skm1 = sk; ck = cn; sk = sn;
            Tsh[k * 64 + tid]        = cn;
            Tsh[(KM + k) * 64 + tid] = sn;
        }
    }
    {
        const float sc1 = 50.0f / 4096.0f;          // (1/tau)/n
        const float sc2 = 2.0f * 50.0f / 4096.0f;
        for (int j = 0; j < NJ; ++j) {
            int   k     = (j <= KM) ? j : (j - KM);
            float lam_s = ws[L_OFF + s * (KM + 1) + k];   // uniform -> scalar
            float x     = ws[UV_OFF + j * NB + tid];      // coalesced, L2-hot
            Psh[j * NB + tid] = lam_s * x * ((j == 0) ? sc1 : sc2);
        }
    }
    __syncthreads();

    int ig = tid >> 5;      // 8 i's: i0 + ig*8 .. +7
    int bg = tid & 31;      // 8 b's: bg + 32*c  (lane-consecutive LDS reads)
    float acc[8][8];
#pragma unroll
    for (int a = 0; a < 8; ++a)
#pragma unroll
        for (int c = 0; c < 8; ++c) acc[a][c] = 0.0f;

    for (int j = 0; j < NJ; ++j) {
        float4 t0 = *reinterpret_cast<const float4*>(&Tsh[j * 64 + ig * 8]);
        float4 t1 = *reinterpret_cast<const float4*>(&Tsh[j * 64 + ig * 8 + 4]);
        float t[8] = {t0.x, t0.y, t0.z, t0.w, t1.x, t1.y, t1.z, t1.w};
        float p[8];
#pragma unroll
        for (int c = 0; c < 8; ++c) p[c] = Psh[j * NB + bg + 32 * c];
#pragma unroll
        for (int a = 0; a < 8; ++a)
#pragma unroll
            for (int c = 0; c < 8; ++c)
                acc[a][c] += t[a] * p[c];
    }

    float* rbase = out + 61 + ((size_t)s * NN + i0) * NB;
#pragma unroll
    for (int a = 0; a < 8; ++a) {
        size_t row = (size_t)(ig * 8 + a) * NB;
#pragma unroll
        for (int c = 0; c < 8; ++c)
            rbase[row + bg + 32 * c] = acc[a][c];   // coalesced per (a,c)
    }
}

extern "C" void kernel_launch(void* const* d_in, const int* in_sizes, int n_in,
                              void* d_out, int out_size, void* d_ws, size_t ws_size,
                              hipStream_t stream) {
    (void)in_sizes; (void)n_in; (void)out_size; (void)ws_size;
    const float* theta = (const float*)d_in[0];
    const float* W     = (const float*)d_in[1];
    float* out = (float*)d_out;
    float* ws  = (float*)d_ws;

    rnn_ring_kA<<<dim3(1),           dim3(256), 0, stream>>>(W, ws, out);
    rnn_ring_kB<<<dim3(NB),          dim3(256), 0, stream>>>(theta, ws);
    rnn_ring_kC<<<dim3(NSTEPS * 64), dim3(256), 0, stream>>>(ws, out);
}

// Round 3
// 79.304 us; speedup vs baseline: 1.3128x; 1.3128x over previous
//
#include <hip/hip_runtime.h>
#include <math.h>

// Spectral solution of the ring RNN:
//   r_record[s] = M^s (h / tau),  M = (1-c) I + c W,  c = dt/tau = 0.05
// W circulant, h von-Mises bump with Fourier amplitudes e^{-b}I_k(b), b~1.62:
// mode k=9 contributes ~8e-6 absolute to r (values ~50, threshold 1.0), so
// KM=8 harmonics suffice.
//   r_s[i,b] = lam_0^s*P0(b) + sum_{k=1..8} lam_k^s*(Pc_k(b) cos k phi_i
//                                                  + Ps_k(b) sin k phi_i)
// with sc folded into P at prep time. Synthesis kernel: no LDS, wave-uniform
// Chebyshev basis in registers, float4 nontemporal stores (1 KB/wave/instr).

#define NN      4096
#define NB      256
#define NSTEPS  61
#define KM      8
#define NJ      17            // 1 + KM cos + KM sin

#define PHI_STEP 0.0015339807878856412f   // 2*pi/4096
#define INV_K2   1.6211389382774044f      // 1/kappa^2 = 16/pi^2

typedef float fx4 __attribute__((ext_vector_type(4)));  // nontemporal-storable

// ws layout (floats)
#define L_OFF   64            // lambda powers: [61][KM+1]
#define UV_OFF  2048          // scaled coefficients: [NJ][NB]

__device__ __forceinline__ float phiF(int i) { return PHI_STEP * (float)i; }

// --- prep: block 256 = spectrum of W row0 -> lambda^s table + t_record;
//           blocks 0..255 = mode projections of h(theta_b), scale folded ---
__global__ void __launch_bounds__(256)
rnn_ring_prep(const float* __restrict__ theta, const float* __restrict__ W,
              float* __restrict__ ws, float* __restrict__ out) {
    int tid = threadIdx.x;
    __shared__ float red[4][NJ];
    int wid = tid >> 6, lane = tid & 63;

    if (blockIdx.x == 256) {
        // ---- spectrum of W (row 0) ----
        float acc[KM + 1];
#pragma unroll
        for (int k = 0; k <= KM; ++k) acc[k] = 0.0f;
        for (int j = tid; j < NN; j += 256) {
            float w  = W[j];
            float c1 = cosf(phiF(j));
            acc[0] += w;
            acc[1] += w * c1;
            float ckm1 = 1.0f, ck = c1;
#pragma unroll
            for (int k = 2; k <= KM; ++k) {
                float cn = 2.0f * c1 * ck - ckm1;
                ckm1 = ck; ck = cn;
                acc[k] += w * cn;
            }
        }
#pragma unroll
        for (int k = 0; k <= KM; ++k) {
            float x = acc[k];
            x += __shfl_xor(x, 32); x += __shfl_xor(x, 16); x += __shfl_xor(x, 8);
            x += __shfl_xor(x, 4);  x += __shfl_xor(x, 2);  x += __shfl_xor(x, 1);
            acc[k] = x;
        }
        if (lane == 0) {
#pragma unroll
            for (int k = 0; k <= KM; ++k) red[wid][k] = acc[k];
        }
        __syncthreads();
        if (tid <= KM) {
            float wk  = red[0][tid] + red[1][tid] + red[2][tid] + red[3][tid];
            float lam = 0.95f + 0.05f * wk;     // (1-c) + c*w_k
            float p = 1.0f;
            for (int s = 0; s < NSTEPS; ++s) {
                ws[L_OFF + s * (KM + 1) + tid] = p;
                p *= lam;
            }
        }
        if (tid >= 64 && tid < 64 + NSTEPS)
            out[tid - 64] = 0.001f * (float)(tid - 64);   // t_record
    } else {
        // ---- projections of h for batch element b ----
        int b = blockIdx.x;
        float th = theta[b];
        float uv[NJ];
#pragma unroll
        for (int j = 0; j < NJ; ++j) uv[j] = 0.0f;
        for (int i = tid; i < NN; i += 256) {
            float ph = phiF(i);
            float hh = expf((cosf(ph - th) - 1.0f) * INV_K2);
            float c1 = cosf(ph), s1 = sinf(ph);
            uv[0]      += hh;
            uv[1]      += hh * c1;
            uv[KM + 1] += hh * s1;
            float ckm1 = 1.0f, skm1 = 0.0f, ck = c1, sk = s1;
#pragma unroll
            for (int k = 2; k <= KM; ++k) {
                float cn = 2.0f * c1 * ck - ckm1;
                float sn = 2.0f * c1 * sk - skm1;
                ckm1 = ck; skm1 = sk; ck = cn; sk = sn;
                uv[k]      += hh * cn;
                uv[KM + k] += hh * sn;
            }
        }
#pragma unroll
        for (int j = 0; j < NJ; ++j) {
            float x = uv[j];
            x += __shfl_xor(x, 32); x += __shfl_xor(x, 16); x += __shfl_xor(x, 8);
            x += __shfl_xor(x, 4);  x += __shfl_xor(x, 2);  x += __shfl_xor(x, 1);
            uv[j] = x;
        }
        if (lane == 0) {
#pragma unroll
            for (int j = 0; j < NJ; ++j) red[wid][j] = uv[j];
        }
        __syncthreads();
        if (tid < NJ) {
            float x = red[0][tid] + red[1][tid] + red[2][tid] + red[3][tid];
            float sc = (tid == 0) ? (50.0f / 4096.0f) : (100.0f / 4096.0f);
            ws[UV_OFF + tid * NB + b] = x * sc;
        }
    }
}

// --- synthesis: block = (s, 64-row i-tile). No LDS. Lane l owns cols
//     4l..4l+3; each wave produces 16 full rows; 1KB float4 stores. ---
__global__ void __launch_bounds__(256)
rnn_ring_kC(const float* __restrict__ ws, float* __restrict__ out) {
    int s    = blockIdx.x >> 6;
    int i0   = (blockIdx.x & 63) << 6;
    int lane = threadIdx.x & 63;
    int w    = threadIdx.x >> 6;

    float lam[KM + 1];
#pragma unroll
    for (int k = 0; k <= KM; ++k) lam[k] = ws[L_OFF + s * (KM + 1) + k];

    fx4 P[NJ];
#pragma unroll
    for (int j = 0; j < NJ; ++j) {
        fx4 v = *reinterpret_cast<const fx4*>(&ws[UV_OFF + j * NB + 4 * lane]);
        float m = (j <= KM) ? lam[j] : lam[j - KM];
        P[j] = v * m;
    }

    float* rbase = out + NSTEPS + ((size_t)s * NN + i0) * NB + 4 * lane;
#pragma unroll
    for (int r = 0; r < 16; ++r) {
        int   row = r * 4 + w;
        float ph  = phiF(i0 + row);
        float c1  = cosf(ph), s1 = sinf(ph);

        fx4 a = P[0] + c1 * P[1] + s1 * P[KM + 1];
        float ckm1 = 1.0f, skm1 = 0.0f, ck = c1, sk = s1;
#pragma unroll
        for (int k = 2; k <= KM; ++k) {
            float cn = 2.0f * c1 * ck - ckm1;
            float sn = 2.0f * c1 * sk - skm1;
            ckm1 = ck; ck = cn; skm1 = sk; sk = sn;
            a += cn * P[k] + sn * P[KM + k];
        }
        __builtin_nontemporal_store(a,
            reinterpret_cast<fx4*>(rbase + (size_t)row * NB));
    }
}

extern "C" void kernel_launch(void* const* d_in, const int* in_sizes, int n_in,
                              void* d_out, int out_size, void* d_ws, size_t ws_size,
                              hipStream_t stream) {
    (void)in_sizes; (void)n_in; (void)out_size; (void)ws_size;
    const float* theta = (const float*)d_in[0];
    const float* W     = (const float*)d_in[1];
    float* out = (float*)d_out;
    float* ws  = (float*)d_ws;

    rnn_ring_prep<<<dim3(257),         dim3(256), 0, stream>>>(theta, W, ws, out);
    rnn_ring_kC <<<dim3(NSTEPS * 64),  dim3(256), 0, stream>>>(ws, out);
}